// Round 3
// baseline (181.348 us; speedup 1.0000x reference)
//
#include <hip/hip_runtime.h>

// Spatial transformer: trilinear warp of src by flow, border padding.
// D=160, H=192, W=160.  u = (idx + flow) * S/(S-1) - 0.5, clamp, trilinear.
//
// Lineage:
//   R5: 4-parity bf16 table, 2x8B gather (same line)  -> 51us
//   R6: same table, 1x16B gather, linear+XCD swizzle  -> 50us  (req count free)
//   R7: z-parity table (2 lines/voxel) + d-slab order -> 61us, FETCH 71->45MB
//   R8: 4-parity + d-slab order (L2-resident window)  -> 52.5us, FETCH 59.5MB
// Conclusion: gather cost is ~6 cyc/lane-gather INDEPENDENT of backing tier
// (L2-resident vs L3 vs HBM all ~equal) => either latency-bound at fixed
// outstanding-miss capacity, or a hard TA/TCP scatter rate. R9 discriminates:
// 8 voxels/thread = 8 gathers in flight per lane (2x MLP). Also drops the
// xe cndmask path via the exact border identity (xb=WW-2, fx=1.0).

#define DD 160
#define HH 192
#define WW 160
#define DHW (DD * HH * WW)
#define ZP (DD / 2)   /* 80 */
#define YP (HH / 2)   /* 96 */
#define COPY_ENTRIES (ZP * YP * WW)            /* 1,228,800 entries x 8B */
#define WS_NEEDED (4ULL * COPY_ENTRIES * 8ULL) /* 39,321,600 B */

typedef unsigned int u32x4 __attribute__((ext_vector_type(4)));

__device__ __forceinline__ unsigned short bf16_rn(float f) {
    unsigned int u = __float_as_uint(f);
    return (unsigned short)((u + 0x7FFFu + ((u >> 16) & 1u)) >> 16);
}

// ---------------- prepass: build 4 parity-packed bf16 stencil copies ----------------
// copy(cz,cy) entry [zp][yp][x] (2 uints):
//   u0 = bf(z0,y0,x) | bf(z1,y0,x)<<16
//   u1 = bf(z0,y1,x) | bf(z1,y1,x)<<16
// where z0=2*zp+cz, z1=min(z0+1,DD-1), y0=2*yp+cy, y1=min(y0+1,HH-1).
__global__ __launch_bounds__(256) void pack_kernel(
    const float* __restrict__ src, unsigned int* __restrict__ tab)
{
    int b = blockIdx.x;                            // grid 1200 = 8 * 150
    int nb = (b & 7) * 150 + (b >> 3);
    int t = nb * 256 + (int)threadIdx.x;           // 307,200 threads
    int xq  = t % (WW / 4);
    int rem = t / (WW / 4);
    int yp  = rem % YP;
    int zp  = rem / YP;                            // [0,80)
    int x = xq * 4;

    int zs[3] = { 2 * zp, 2 * zp + 1, min(2 * zp + 2, DD - 1) };
    int ys[3] = { 2 * yp, 2 * yp + 1, min(2 * yp + 2, HH - 1) };

    float4 r[3][3];
    #pragma unroll
    for (int i = 0; i < 3; ++i)
        #pragma unroll
        for (int j = 0; j < 3; ++j)
            r[i][j] = *(const float4*)(src + ((size_t)zs[i] * HH + ys[j]) * WW + x);

    #pragma unroll
    for (int cz = 0; cz < 2; ++cz)
        #pragma unroll
        for (int cy = 0; cy < 2; ++cy) {
            unsigned int e[8];
            #pragma unroll
            for (int k = 0; k < 4; ++k) {
                float a  = ((const float*)&r[cz    ][cy    ])[k];
                float b2 = ((const float*)&r[cz + 1][cy    ])[k];
                float c  = ((const float*)&r[cz    ][cy + 1])[k];
                float d  = ((const float*)&r[cz + 1][cy + 1])[k];
                e[2 * k]     = (unsigned int)bf16_rn(a) | ((unsigned int)bf16_rn(b2) << 16);
                e[2 * k + 1] = (unsigned int)bf16_rn(c) | ((unsigned int)bf16_rn(d) << 16);
            }
            unsigned int* dst = tab +
                ((size_t)(cz * 2 + cy) * COPY_ENTRIES + ((size_t)zp * YP + yp) * WW + x) * 2;
            *(uint4*)(dst)     = make_uint4(e[0], e[1], e[2], e[3]);
            *(uint4*)(dst + 4) = make_uint4(e[4], e[5], e[6], e[7]);
        }
}

// ---------------- main: 8 voxels/thread, 8 gathers in flight ----------------
__global__ __launch_bounds__(256) void warp8_kernel(
    const unsigned int* __restrict__ tab,
    const float* __restrict__ flow,
    float* __restrict__ out)
{
    // R6's proven mapping: XCD k gets contiguous block range -> its table
    // slab stays warm. grid 2400 = 8 * 300.
    int b = blockIdx.x;
    int nb = (b & 7) * 300 + (b >> 3);
    int base = (nb * 256 + (int)threadIdx.x) * 8;   // 8 consecutive x voxels

    int w = base % WW;        // w in {0,8,...,152}; w+7 <= 159 (8 | WW)
    int tmp = base / WW;
    int h = tmp % HH;
    int d = tmp / HH;

    // flow: 6x float4 streaming loads (compiler-scheduled, consumed below)
    const float4 fza = *(const float4*)(flow + base);
    const float4 fzb = *(const float4*)(flow + base + 4);
    const float4 fya = *(const float4*)(flow + DHW + base);
    const float4 fyb = *(const float4*)(flow + DHW + base + 4);
    const float4 fxa = *(const float4*)(flow + 2 * DHW + base);
    const float4 fxb = *(const float4*)(flow + 2 * DHW + base + 4);
    const float* flz[2] = { (const float*)&fza, (const float*)&fzb };
    const float* fly[2] = { (const float*)&fya, (const float*)&fyb };
    const float* flx[2] = { (const float*)&fxa, (const float*)&fxb };

    const float SX = (float)WW / (float)(WW - 1);
    const float SY = (float)HH / (float)(HH - 1);
    const float SZ = (float)DD / (float)(DD - 1);

    float fx[8], fy[8], fz[8];
    const unsigned int* pp[8];

    // ---- phase 1: ALL addresses & weights (drains flow before any asm gather,
    //      so compiler waitcnts can't interact with the manual vmcnt counts) ----
    #pragma unroll
    for (int v = 0; v < 8; ++v) {
        float ux = fmaf((float)(w + v) + flx[v >> 2][v & 3], SX, -0.5f);
        float uy = fmaf((float)h + fly[v >> 2][v & 3],       SY, -0.5f);
        float uz = fmaf((float)d + flz[v >> 2][v & 3],       SZ, -0.5f);
        ux = fminf(fmaxf(ux, 0.0f), (float)(WW - 1));
        uy = fminf(fmaxf(uy, 0.0f), (float)(HH - 1));
        uz = fminf(fmaxf(uz, 0.0f), (float)(DD - 1));
        float x0f = floorf(ux), y0f = floorf(uy), z0f = floorf(uz);
        fy[v] = uy - y0f; fz[v] = uz - z0f;
        int x0 = (int)x0f, y0 = (int)y0f, z0 = (int)z0f;
        // border identity: x0==WW-1 implies ux==WW-1, fx would be 0; using
        // entries (WW-2, WW-1) with fx=1.0 returns the WW-1 sample exactly
        // (<=1 ulp f32, vs 1.56e-2 tolerance). Kills the xe cndmask path.
        fx[v] = (x0 == WW - 1) ? 1.0f : (ux - x0f);
        int xb = min(x0, WW - 2);          // entries xb, xb+1
        int zp = z0 >> 1, cz = z0 & 1;
        int yp = y0 >> 1, cy = y0 & 1;
        pp[v] = tab + ((size_t)((cz << 1) | cy) * COPY_ENTRIES
                       + ((size_t)zp * YP + yp) * WW + xb) * 2;
    }

    // ---- phase 2: 8 gathers in flight (ONE dwordx4 per voxel) ----
    u32x4 q[8];
    #pragma unroll
    for (int v = 0; v < 8; ++v)
        asm volatile("global_load_dwordx4 %0, %1, off"
                     : "=v"(q[v]) : "v"(pp[v]));

    // ---- phase 3: progressive waits (vmcnt retires in issue order) + interp ----
    float res[8];
    #pragma unroll
    for (int v = 0; v < 8; ++v) {
        if (v == 0) asm volatile("s_waitcnt vmcnt(7)" : "+v"(q[0]) :: "memory");
        if (v == 1) asm volatile("s_waitcnt vmcnt(6)" : "+v"(q[1]) :: "memory");
        if (v == 2) asm volatile("s_waitcnt vmcnt(5)" : "+v"(q[2]) :: "memory");
        if (v == 3) asm volatile("s_waitcnt vmcnt(4)" : "+v"(q[3]) :: "memory");
        if (v == 4) asm volatile("s_waitcnt vmcnt(3)" : "+v"(q[4]) :: "memory");
        if (v == 5) asm volatile("s_waitcnt vmcnt(2)" : "+v"(q[5]) :: "memory");
        if (v == 6) asm volatile("s_waitcnt vmcnt(1)" : "+v"(q[6]) :: "memory");
        if (v == 7) asm volatile("s_waitcnt vmcnt(0)" : "+v"(q[7]) :: "memory");

        unsigned int lox = q[v].x;   // entry xb  : (z0,y0),(z1,y0)
        unsigned int loy = q[v].y;   //            (z0,y1),(z1,y1)
        unsigned int hix = q[v].z;   // entry xb+1
        unsigned int hiy = q[v].w;

        float c000 = __uint_as_float(lox << 16);
        float c100 = __uint_as_float(lox & 0xFFFF0000u);
        float c010 = __uint_as_float(loy << 16);
        float c110 = __uint_as_float(loy & 0xFFFF0000u);
        float c001 = __uint_as_float(hix << 16);
        float c101 = __uint_as_float(hix & 0xFFFF0000u);
        float c011 = __uint_as_float(hiy << 16);
        float c111 = __uint_as_float(hiy & 0xFFFF0000u);

        float r00 = fmaf(fx[v], c001 - c000, c000);
        float r01 = fmaf(fx[v], c011 - c010, c010);
        float r10 = fmaf(fx[v], c101 - c100, c100);
        float r11 = fmaf(fx[v], c111 - c110, c110);
        float r0  = fmaf(fy[v], r01 - r00, r00);
        float r1  = fmaf(fy[v], r11 - r10, r10);
        res[v]    = fmaf(fz[v], r1 - r0, r0);
    }

    *(float4*)(out + base)     = make_float4(res[0], res[1], res[2], res[3]);
    *(float4*)(out + base + 4) = make_float4(res[4], res[5], res[6], res[7]);
}

// ---------------- fallback (proven R2 kernel) if ws too small ----------------
struct __align__(4) F2 { float a, b; };

__global__ __launch_bounds__(256) void warp_direct_kernel(
    const float* __restrict__ src,
    const float* __restrict__ flow,
    float* __restrict__ out)
{
    int b = blockIdx.x;
    int nb = (b & 7) * 600 + (b >> 3);
    int base = (nb * 256 + (int)threadIdx.x) * 4;

    int w = base % WW;
    int tmp = base / WW;
    int h = tmp % HH;
    int d = tmp / HH;

    const float4 f0  = *(const float4*)(flow + base);
    const float4 f1  = *(const float4*)(flow + DHW + base);
    const float4 f2v = *(const float4*)(flow + 2 * DHW + base);
    const float* f0p = (const float*)&f0;
    const float* f1p = (const float*)&f1;
    const float* f2p = (const float*)&f2v;

    const float SX = (float)WW / (float)(WW - 1);
    const float SY = (float)HH / (float)(HH - 1);
    const float SZ = (float)DD / (float)(DD - 1);

    float res[4];
    #pragma unroll
    for (int v = 0; v < 4; ++v) {
        float ux = fmaf((float)(w + v) + f2p[v], SX, -0.5f);
        float uy = fmaf((float)h + f1p[v],       SY, -0.5f);
        float uz = fmaf((float)d + f0p[v],       SZ, -0.5f);
        ux = fminf(fmaxf(ux, 0.0f), (float)(WW - 1));
        uy = fminf(fmaxf(uy, 0.0f), (float)(HH - 1));
        uz = fminf(fmaxf(uz, 0.0f), (float)(DD - 1));
        float x0f = floorf(ux), y0f = floorf(uy), z0f = floorf(uz);
        float fx = ux - x0f, fy = uy - y0f, fz = uz - z0f;
        int x0 = (int)x0f, y0 = (int)y0f, z0 = (int)z0f;
        int y1 = min(y0 + 1, HH - 1);
        int z1 = min(z0 + 1, DD - 1);
        int xb = min(x0, WW - 2);
        bool xe = (x0 == WW - 1);
        F2 q00 = *(const F2*)(src + ((size_t)z0 * HH + y0) * WW + xb);
        F2 q01 = *(const F2*)(src + ((size_t)z0 * HH + y1) * WW + xb);
        F2 q10 = *(const F2*)(src + ((size_t)z1 * HH + y0) * WW + xb);
        F2 q11 = *(const F2*)(src + ((size_t)z1 * HH + y1) * WW + xb);
        float c000 = xe ? q00.b : q00.a, c001 = q00.b;
        float c010 = xe ? q01.b : q01.a, c011 = q01.b;
        float c100 = xe ? q10.b : q10.a, c101 = q10.b;
        float c110 = xe ? q11.b : q11.a, c111 = q11.b;
        float r00 = fmaf(fx, c001 - c000, c000);
        float r01 = fmaf(fx, c011 - c010, c010);
        float r10 = fmaf(fx, c101 - c100, c100);
        float r11 = fmaf(fx, c111 - c110, c110);
        float r0  = fmaf(fy, r01 - r00, r00);
        float r1  = fmaf(fy, r11 - r10, r10);
        res[v]    = fmaf(fz, r1 - r0, r0);
    }
    *(float4*)(out + base) = make_float4(res[0], res[1], res[2], res[3]);
}

extern "C" void kernel_launch(void* const* d_in, const int* in_sizes, int n_in,
                              void* d_out, int out_size, void* d_ws, size_t ws_size,
                              hipStream_t stream) {
    const float* src  = (const float*)d_in[0];   // [1,1,D,H,W]
    const float* flow = (const float*)d_in[1];   // [1,3,D,H,W]
    // d_in[2] identity grid: unused (recomputed)
    float* out = (float*)d_out;

    if (ws_size >= WS_NEEDED) {
        unsigned int* tab = (unsigned int*)d_ws;
        pack_kernel<<<(ZP * YP * (WW / 4)) / 256, 256, 0, stream>>>(src, tab);
        warp8_kernel<<<DHW / 8 / 256, 256, 0, stream>>>(tab, flow, out);
    } else {
        warp_direct_kernel<<<DHW / 4 / 256, 256, 0, stream>>>(src, flow, out);
    }
}

// Round 4
// 175.041 us; speedup vs baseline: 1.0360x; 1.0360x over previous
//
#include <hip/hip_runtime.h>

// Spatial transformer: trilinear warp of src by flow, border padding.
// D=160, H=192, W=160.  u = (idx + flow) * S/(S-1) - 0.5, clamp, trilinear.
//
// Lineage:
//   R5/R6: 4-parity bf16 table, 1 line/voxel global gather -> 50-51us
//   R7/R8/R9: tier residency, MLP, ordering all ~null => scattered-line
//   service rate (~6 cyc/line/CU) is the wall; 1 line/voxel irreducible
//   for global gather (flow i.i.d. => no line sharing).
// R10: gather from LDS instead. Block = 16^3 output tile; stage 32^3 bf16
// window (tile + 8-halo) into 64KB LDS from a padded bf16 src volume
// (prepass). 8 stencil taps = ds_read_u16. Outliers (|disp|>8, ~2% voxels)
// take the proven global f32 slow path under exec mask. Staged line traffic
// ~1.5M full lines vs 4.9M scattered quarter-lines.

#define DD 160
#define HH 192
#define WW 160
#define DHW (DD * HH * WW)
#define PW 192                                  /* padded width: slot s <-> gx = clamp(s-8) */
#define NROWS (DD * HH)                          /* 30720 */
#define WS_NEEDED ((size_t)NROWS * PW * 2)       /* 11,796,480 B */

__device__ __forceinline__ unsigned short bf16_rn(float f) {
    unsigned int u = __float_as_uint(f);
    return (unsigned short)((u + 0x7FFFu + ((u >> 16) & 1u)) >> 16);
}

// ---------------- prepass: padded bf16 volume ----------------
// bsrc[row][s] = bf16(src[row][clamp(s-8, 0, WW-1)]), s in [0,192)
__global__ __launch_bounds__(256) void pack_bf16_kernel(
    const float* __restrict__ src, unsigned short* __restrict__ bsrc)
{
    int t = blockIdx.x * 256 + (int)threadIdx.x;  // 737,280 threads = 2880 blocks
    int q = t % (PW / 8);                          // 24 chunks of 8 slots
    int row = t / (PW / 8);                        // [0, 30720)
    const float* srow = src + (size_t)row * WW;
    int j0 = q * 8;

    unsigned int e[4];
    #pragma unroll
    for (int i = 0; i < 4; ++i) {
        int ga = min(max(j0 + 2 * i     - 8, 0), WW - 1);
        int gb = min(max(j0 + 2 * i + 1 - 8, 0), WW - 1);
        e[i] = (unsigned int)bf16_rn(srow[ga]) | ((unsigned int)bf16_rn(srow[gb]) << 16);
    }
    *(uint4*)(bsrc + (size_t)row * PW + j0) = make_uint4(e[0], e[1], e[2], e[3]);
}

// ---------------- main: LDS-staged trilinear ----------------
struct __align__(4) F2 { float a, b; };

__global__ __launch_bounds__(512) void warp_lds_kernel(
    const unsigned short* __restrict__ bsrc,
    const float* __restrict__ src,
    const float* __restrict__ flow,
    float* __restrict__ out)
{
    __shared__ unsigned short sm[32 * 32 * 32];   // 64 KB: [dz][dy][dx], dz,dy,dx in [0,32)

    int tile = blockIdx.x;                        // grid 1200 = 10 x 12 x 10
    int txq = tile % 10;
    int rem = tile / 10;
    int tyq = rem % 12;
    int tzq = rem / 12;
    int bx = txq * 16, by = tyq * 16, bz = tzq * 16;

    int t = (int)threadIdx.x;
    int lane = t & 63;
    int wave = t >> 6;                            // 8 waves

    // ---- stage window: z,y in [b-8, b+24), x slots [bx, bx+32) of padded buf ----
    // 64 wave-instrs total (8 per wave); instr j stages 16 rows x 64B; lane L:
    // row = j*16 + L/4, 16B chunk L%4. Clamped (gz,gy) rows reproduce border.
    #pragma unroll
    for (int k = 0; k < 8; ++k) {
        int j = wave * 8 + k;                     // 0..63
        int row = j * 16 + (lane >> 2);           // 0..1023 = zz*32+yy
        int zz = row >> 5;
        int yy = row & 31;
        int gz = min(max(bz - 8 + zz, 0), DD - 1);
        int gy = min(max(by - 8 + yy, 0), HH - 1);
        const uint4 vv = *(const uint4*)(bsrc + (size_t)(gz * HH + gy) * PW + bx + (lane & 3) * 8);
        *(uint4*)&sm[row * 32 + (lane & 3) * 8] = vv;
    }
    __syncthreads();

    const float SX = (float)WW / (float)(WW - 1);
    const float SY = (float)HH / (float)(HH - 1);
    const float SZ = (float)DD / (float)(DD - 1);

    // ---- 2 passes x 4 voxels/thread: 512*2*4 = 4096 = 16^3 ----
    #pragma unroll
    for (int p = 0; p < 2; ++p) {
        int vi = (p * 512 + t) * 4;               // tile-linear voxel index
        int tx = vi & 15;
        int ty = (vi >> 4) & 15;
        int tz = vi >> 8;
        int gw = bx + tx, gh = by + ty, gd = bz + tz;
        int gbase = (gd * HH + gh) * WW + gw;

        const float4 fz4 = *(const float4*)(flow + gbase);            // -> D/z
        const float4 fy4 = *(const float4*)(flow + DHW + gbase);      // -> H/y
        const float4 fx4 = *(const float4*)(flow + 2 * DHW + gbase);  // -> W/x
        const float* pz = (const float*)&fz4;
        const float* py = (const float*)&fy4;
        const float* px = (const float*)&fx4;

        float res[4];
        #pragma unroll
        for (int v = 0; v < 4; ++v) {
            float ux = fmaf((float)(gw + v) + px[v], SX, -0.5f);
            float uy = fmaf((float)gh + py[v],       SY, -0.5f);
            float uz = fmaf((float)gd + pz[v],       SZ, -0.5f);
            ux = fminf(fmaxf(ux, 0.0f), (float)(WW - 1));
            uy = fminf(fmaxf(uy, 0.0f), (float)(HH - 1));
            uz = fminf(fmaxf(uz, 0.0f), (float)(DD - 1));
            float x0f = floorf(ux), y0f = floorf(uy), z0f = floorf(uz);
            float wx = ux - x0f, wy = uy - y0f, wz = uz - z0f;
            int x0 = (int)x0f, y0 = (int)y0f, z0 = (int)z0f;

            int dx = x0 - bx + 8;                 // window-local coords
            int dy = y0 - by + 8;
            int dz = z0 - bz + 8;
            // main path iff [d,d+1] within 32-slot window (d<=30). Clamped
            // staging means slot d+1 holds the border-clamped neighbor, so
            // volume borders are exact.
            bool ok = ((unsigned)dx <= 30u) & ((unsigned)dy <= 30u) & ((unsigned)dz <= 30u);

            float r;
            if (ok) {
                int idx = dz * 1024 + dy * 32 + dx;
                float c000 = __uint_as_float((unsigned)sm[idx       ] << 16);
                float c001 = __uint_as_float((unsigned)sm[idx + 1   ] << 16);
                float c010 = __uint_as_float((unsigned)sm[idx + 32  ] << 16);
                float c011 = __uint_as_float((unsigned)sm[idx + 33  ] << 16);
                float c100 = __uint_as_float((unsigned)sm[idx + 1024] << 16);
                float c101 = __uint_as_float((unsigned)sm[idx + 1025] << 16);
                float c110 = __uint_as_float((unsigned)sm[idx + 1056] << 16);
                float c111 = __uint_as_float((unsigned)sm[idx + 1057] << 16);
                float r00 = fmaf(wx, c001 - c000, c000);
                float r01 = fmaf(wx, c011 - c010, c010);
                float r10 = fmaf(wx, c101 - c100, c100);
                float r11 = fmaf(wx, c111 - c110, c110);
                float r0  = fmaf(wy, r01 - r00, r00);
                float r1  = fmaf(wy, r11 - r10, r10);
                r = fmaf(wz, r1 - r0, r0);
            } else {
                // slow path (~2% of voxels): proven border-clamped f32 gather
                int y1 = min(y0 + 1, HH - 1);
                int z1 = min(z0 + 1, DD - 1);
                int xb = min(x0, WW - 2);
                bool xe = (x0 == WW - 1);
                F2 q00 = *(const F2*)(src + ((size_t)z0 * HH + y0) * WW + xb);
                F2 q01 = *(const F2*)(src + ((size_t)z0 * HH + y1) * WW + xb);
                F2 q10 = *(const F2*)(src + ((size_t)z1 * HH + y0) * WW + xb);
                F2 q11 = *(const F2*)(src + ((size_t)z1 * HH + y1) * WW + xb);
                float c000 = xe ? q00.b : q00.a, c001 = q00.b;
                float c010 = xe ? q01.b : q01.a, c011 = q01.b;
                float c100 = xe ? q10.b : q10.a, c101 = q10.b;
                float c110 = xe ? q11.b : q11.a, c111 = q11.b;
                float r00 = fmaf(wx, c001 - c000, c000);
                float r01 = fmaf(wx, c011 - c010, c010);
                float r10 = fmaf(wx, c101 - c100, c100);
                float r11 = fmaf(wx, c111 - c110, c110);
                float r0  = fmaf(wy, r01 - r00, r00);
                float r1  = fmaf(wy, r11 - r10, r10);
                r = fmaf(wz, r1 - r0, r0);
            }
            res[v] = r;
        }
        *(float4*)(out + gbase) = make_float4(res[0], res[1], res[2], res[3]);
    }
}

// ---------------- fallback (proven R2 kernel) if ws too small ----------------
__global__ __launch_bounds__(256) void warp_direct_kernel(
    const float* __restrict__ src,
    const float* __restrict__ flow,
    float* __restrict__ out)
{
    int b = blockIdx.x;
    int nb = (b & 7) * 600 + (b >> 3);
    int base = (nb * 256 + (int)threadIdx.x) * 4;

    int w = base % WW;
    int tmp = base / WW;
    int h = tmp % HH;
    int d = tmp / HH;

    const float4 f0  = *(const float4*)(flow + base);
    const float4 f1  = *(const float4*)(flow + DHW + base);
    const float4 f2v = *(const float4*)(flow + 2 * DHW + base);
    const float* f0p = (const float*)&f0;
    const float* f1p = (const float*)&f1;
    const float* f2p = (const float*)&f2v;

    const float SX = (float)WW / (float)(WW - 1);
    const float SY = (float)HH / (float)(HH - 1);
    const float SZ = (float)DD / (float)(DD - 1);

    float res[4];
    #pragma unroll
    for (int v = 0; v < 4; ++v) {
        float ux = fmaf((float)(w + v) + f2p[v], SX, -0.5f);
        float uy = fmaf((float)h + f1p[v],       SY, -0.5f);
        float uz = fmaf((float)d + f0p[v],       SZ, -0.5f);
        ux = fminf(fmaxf(ux, 0.0f), (float)(WW - 1));
        uy = fminf(fmaxf(uy, 0.0f), (float)(HH - 1));
        uz = fminf(fmaxf(uz, 0.0f), (float)(DD - 1));
        float x0f = floorf(ux), y0f = floorf(uy), z0f = floorf(uz);
        float fx = ux - x0f, fy = uy - y0f, fz = uz - z0f;
        int x0 = (int)x0f, y0 = (int)y0f, z0 = (int)z0f;
        int y1 = min(y0 + 1, HH - 1);
        int z1 = min(z0 + 1, DD - 1);
        int xb = min(x0, WW - 2);
        bool xe = (x0 == WW - 1);
        F2 q00 = *(const F2*)(src + ((size_t)z0 * HH + y0) * WW + xb);
        F2 q01 = *(const F2*)(src + ((size_t)z0 * HH + y1) * WW + xb);
        F2 q10 = *(const F2*)(src + ((size_t)z1 * HH + y0) * WW + xb);
        F2 q11 = *(const F2*)(src + ((size_t)z1 * HH + y1) * WW + xb);
        float c000 = xe ? q00.b : q00.a, c001 = q00.b;
        float c010 = xe ? q01.b : q01.a, c011 = q01.b;
        float c100 = xe ? q10.b : q10.a, c101 = q10.b;
        float c110 = xe ? q11.b : q11.a, c111 = q11.b;
        float r00 = fmaf(fx, c001 - c000, c000);
        float r01 = fmaf(fx, c011 - c010, c010);
        float r10 = fmaf(fx, c101 - c100, c100);
        float r11 = fmaf(fx, c111 - c110, c110);
        float r0  = fmaf(fy, r01 - r00, r00);
        float r1  = fmaf(fy, r11 - r10, r10);
        res[v]    = fmaf(fz, r1 - r0, r0);
    }
    *(float4*)(out + base) = make_float4(res[0], res[1], res[2], res[3]);
}

extern "C" void kernel_launch(void* const* d_in, const int* in_sizes, int n_in,
                              void* d_out, int out_size, void* d_ws, size_t ws_size,
                              hipStream_t stream) {
    const float* src  = (const float*)d_in[0];   // [1,1,D,H,W]
    const float* flow = (const float*)d_in[1];   // [1,3,D,H,W]
    // d_in[2] identity grid: unused (recomputed)
    float* out = (float*)d_out;

    if (ws_size >= WS_NEEDED) {
        unsigned short* bsrc = (unsigned short*)d_ws;
        pack_bf16_kernel<<<(NROWS * (PW / 8)) / 256, 256, 0, stream>>>(src, bsrc);
        warp_lds_kernel<<<1200, 512, 0, stream>>>(bsrc, src, flow, out);
    } else {
        warp_direct_kernel<<<DHW / 4 / 256, 256, 0, stream>>>(src, flow, out);
    }
}